// Round 17
// baseline (76.272 us; speedup 1.0000x reference)
//
#include <hip/hip_runtime.h>

// Backflow: out[b] = sum_d det(g[b,d]) * bf[d]
//   g[b,d][i][j] = sum_h h2[b,h]*Wg[h,d,sel[b,i],j] + bg[d,sel[b,i],j]
// B=8192, O=64, E=16, D=16, H=4.
//
// R17: COOPERATIVE DENSE STAGING — no scattered global reads at all.
// 512-thread blocks = 8 waves = 8 samples. Per det ds the block stages the
// FULL table slice Wg[0..3][ds][0..63][0..15] (16KB) + bg[ds] (4KB) into a
// double-buffered LDS slice via dense coalesced loads (shared by all 8
// samples -> per-CU global traffic 640KB vs R13's 2.56MB of gather).
// Next det's loads are issued one det EARLY into registers, so the one
// __syncthreads per det never waits on L2 (R16's failure mode).
// Per det, per wave: lane (r=lane>>2, c=lane&3) reads its sel_r row from
// the LDS slice (5 ds_read_b128, swizzle c^(o&3)), contracts with h2
// (IDENTICAL fmaf chain -> bit-identical results), writes to a 1KB
// wave-private matrix buffer; quad-ds lanes then read their LU rows
// (wave-internal lgkmcnt ordering, no barrier).
// LU: fully-unrolled triangular unpivoted, zero DS ops, static DPP
// quad_perm broadcasts, column-shift, per-round array retirement.
// Retry (tau=1e-4*mat_max, rare): PER-WAVE, barrier-free, global-gather
// BUILD_ROW rebuild + M = I + 0.5*C16 mix on flagged quads, rescale.
// Lessons: R6/R15 VGPR caps spill. R7 macro hygiene. R12 rule #20.
// R13-R16: the 46us wall is the scattered global gather service path.

template <int CTRL>
__device__ __forceinline__ float dpp_movf(float v) {
    return __int_as_float(__builtin_amdgcn_update_dpp(
        0, __float_as_int(v), CTRL, 0xF, 0xF, true));
}

__global__ __launch_bounds__(512) void backflow_kernel(
    const float* __restrict__ x,    // (B,64)
    const float* __restrict__ W1,   // (64,4)
    const float* __restrict__ b1,   // (4,)
    const float* __restrict__ W2,   // (4,4)
    const float* __restrict__ b2,   // (4,)
    const float* __restrict__ Wg,   // (4,16,64,16)
    const float* __restrict__ bg,   // (16,64,16)
    const float* __restrict__ bf,   // (16,1)
    float* __restrict__ out,        // (B,)
    int B)
{
    const int lane  = threadIdx.x & 63;
    const int wavei = threadIdx.x >> 6;          // 0..7
    const int b     = blockIdx.x * 8 + wavei;    // grid exact: B % 8 == 0
    const int d = lane >> 2;   // LU: det/quad index; LOAD: row index r
    const int l = lane & 3;    // LU: lane-in-quad; LOAD: chunk index c

    __shared__ float4 slice[2][1280];   // 40KB: [h0..h3|bg][o][c] swizzled
    __shared__ float4 Bm[8][64];        // 8KB: per-wave 16x4 matrix bounce
    float4* const bm = Bm[wavei];

    // ---- occupied-orbital mask ----
    const float xv = x[b * 64 + lane];
    const unsigned long long mask = __ballot(xv != 0.0f);
    const bool empty = ((mask & ~1ull) == 0ull);

    // ---- h1 = relu(x @ W1 + b1): 64-lane butterfly ----
    const float4 w1 = reinterpret_cast<const float4*>(W1)[lane];
    float c0 = xv * w1.x, c1 = xv * w1.y, c2 = xv * w1.z, c3 = xv * w1.w;
    #pragma unroll
    for (int off = 32; off >= 1; off >>= 1) {
        c0 += __shfl_xor(c0, off);
        c1 += __shfl_xor(c1, off);
        c2 += __shfl_xor(c2, off);
        c3 += __shfl_xor(c3, off);
    }
    const float h10 = fmaxf(c0 + b1[0], 0.0f);
    const float h11 = fmaxf(c1 + b1[1], 0.0f);
    const float h12 = fmaxf(c2 + b1[2], 0.0f);
    const float h13 = fmaxf(c3 + b1[3], 0.0f);

    // ---- h2 = relu(h1 @ W2 + b2) ----
    float h2[4];
    #pragma unroll
    for (int j = 0; j < 4; ++j) {
        float v = b2[j];
        v = fmaf(h10, W2[0 * 4 + j], v);
        v = fmaf(h11, W2[1 * 4 + j], v);
        v = fmaf(h12, W2[2 * 4 + j], v);
        v = fmaf(h13, W2[3 * 4 + j], v);
        h2[j] = fmaxf(v, 0.0f);
    }

    // ---- LOAD-role selected row: sel_r for r = lane>>2 (skip r set bits) ----
    unsigned long long mr = mask;
    #pragma unroll
    for (int i = 0; i < 15; ++i) if (i < d) mr &= mr - 1;
    const int selr = mr ? (int)__builtin_ctzll(mr) : 0;
    const int sw   = selr * 4 + (l ^ (selr & 3));   // swizzled slice offset

    const float4* wgp = reinterpret_cast<const float4*>(Wg);
    const float4* bgp = reinterpret_cast<const float4*>(bg);

    float R0[16], R1[16], R2[16], R3[16];

    // ---- cooperative slice staging (dense, coalesced, shared by 8 waves) ----
    // 1280 float4 per det: idx<1024 -> Wg[h=idx>>8][ds][o][c]; else bg[ds].
    // Thread t handles idx = t, 512+t, and (t<256) 1024+t.
#define SLICE_LOAD(DS, RV0, RV1, RV2) do {                                   \
        const int t = threadIdx.x;                                           \
        RV0 = wgp[((t >> 8) * 16 + (DS)) * 256 + (t & 255)];                 \
        RV1 = wgp[((2 + (t >> 8)) * 16 + (DS)) * 256 + (t & 255)];           \
        if (t < 256) RV2 = bgp[(DS) * 256 + t];                              \
    } while (0)

#define SLICE_WRITE(P, RV0, RV1, RV2) do {                                   \
        const int t = threadIdx.x;                                           \
        const int o0 = (t & 255) >> 2, cc = t & 3;                           \
        slice[P][(t >> 8) * 256 + o0 * 4 + (cc ^ (o0 & 3))] = RV0;           \
        slice[P][(2 + (t >> 8)) * 256 + o0 * 4 + (cc ^ (o0 & 3))] = RV1;     \
        if (t < 256) {                                                       \
            const int ob = t >> 2, cb = t & 3;                               \
            slice[P][1024 + ob * 4 + (cb ^ (ob & 3))] = RV2;                 \
        } } while (0)

    // ---- per-det: contract from slice, bounce via bm, quad-ds reads rows ----
#define COMPUTE_DET(DS, P) do {                                              \
        const float4 w0  = slice[P][sw];                                     \
        const float4 wv1 = slice[P][256 + sw];                               \
        const float4 w2c = slice[P][512 + sw];                               \
        const float4 w3  = slice[P][768 + sw];                               \
        const float4 wb  = slice[P][1024 + sw];                              \
        float4 a;                                                            \
        a.x = fmaf(h2[0],w0.x, fmaf(h2[1],wv1.x, fmaf(h2[2],w2c.x, fmaf(h2[3],w3.x, wb.x)))); \
        a.y = fmaf(h2[0],w0.y, fmaf(h2[1],wv1.y, fmaf(h2[2],w2c.y, fmaf(h2[3],w3.y, wb.y)))); \
        a.z = fmaf(h2[0],w0.z, fmaf(h2[1],wv1.z, fmaf(h2[2],w2c.z, fmaf(h2[3],w3.z, wb.z)))); \
        a.w = fmaf(h2[0],w0.w, fmaf(h2[1],wv1.w, fmaf(h2[2],w2c.w, fmaf(h2[3],w3.w, wb.w)))); \
        bm[d * 4 + (l ^ (d & 3))] = a;                                       \
        if (d == (DS)) {                                                     \
            _Pragma("unroll")                                                \
            for (int q = 0; q < 4; ++q) {                                    \
                const float4 t0 = bm[(l +  0) * 4 + (q ^ ((l +  0) & 3))];   \
                const float4 t1 = bm[(l +  4) * 4 + (q ^ ((l +  4) & 3))];   \
                const float4 t2 = bm[(l +  8) * 4 + (q ^ ((l +  8) & 3))];   \
                const float4 t3 = bm[(l + 12) * 4 + (q ^ ((l + 12) & 3))];   \
                R0[q*4+0] = t0.x; R0[q*4+1] = t0.y; R0[q*4+2] = t0.z; R0[q*4+3] = t0.w; \
                R1[q*4+0] = t1.x; R1[q*4+1] = t1.y; R1[q*4+2] = t1.z; R1[q*4+3] = t1.w; \
                R2[q*4+0] = t2.x; R2[q*4+1] = t2.y; R2[q*4+2] = t2.z; R2[q*4+3] = t2.w; \
                R3[q*4+0] = t3.x; R3[q*4+1] = t3.y; R3[q*4+2] = t3.z; R3[q*4+3] = t3.w; \
            }                                                                \
        } } while (0)

    {   // ---- det loop: prefetch ds+1 to regs during det ds compute ----
        float4 sr0 = {}, sr1 = {}, sr2 = {};
        SLICE_LOAD(0, sr0, sr1, sr2);
        SLICE_WRITE(0, sr0, sr1, sr2);
        __syncthreads();
        #pragma unroll 1
        for (int ds = 0; ds < 16; ++ds) {
            const int p = ds & 1;
            if (ds < 15) SLICE_LOAD(ds + 1, sr0, sr1, sr2);
            COMPUTE_DET(ds, p);
            if (ds < 15) {
                SLICE_WRITE(p ^ 1, sr0, sr1, sr2);
                __syncthreads();   // slice ds+1 ready; bufs ping-pong safely
            }
        }
    }

    // ---- retry-path rebuild (cold): per-lane global gather (R13 code) ----
#define BUILD_ROW(RW, SQ) do {                                                   \
    const float* base = Wg + ((size_t)d * 64 + (SQ)) * 16;                       \
    const float4* p0 = reinterpret_cast<const float4*>(base);                    \
    const float4* p1 = reinterpret_cast<const float4*>(base + 16384);            \
    const float4* p2 = reinterpret_cast<const float4*>(base + 32768);            \
    const float4* p3 = reinterpret_cast<const float4*>(base + 49152);            \
    const float4* pb = reinterpret_cast<const float4*>(bg + ((size_t)d * 64 + (SQ)) * 16); \
    _Pragma("unroll")                                                            \
    for (int q = 0; q < 4; ++q) {                                                \
        const float4 a0 = p0[q], a1 = p1[q], a2 = p2[q], a3 = p3[q], ab = pb[q]; \
        RW[q*4+0] = fmaf(h2[0],a0.x, fmaf(h2[1],a1.x, fmaf(h2[2],a2.x, fmaf(h2[3],a3.x, ab.x)))); \
        RW[q*4+1] = fmaf(h2[0],a0.y, fmaf(h2[1],a1.y, fmaf(h2[2],a2.y, fmaf(h2[3],a3.y, ab.y)))); \
        RW[q*4+2] = fmaf(h2[0],a0.z, fmaf(h2[1],a1.z, fmaf(h2[2],a2.z, fmaf(h2[3],a3.z, ab.z)))); \
        RW[q*4+3] = fmaf(h2[0],a0.w, fmaf(h2[1],a1.w, fmaf(h2[2],a2.w, fmaf(h2[3],a3.w, ab.w)))); \
    } } while (0)

    // ---- triangular unpivoted LU steps (K static everywhere) ----
#define STEP4(K, DAC, PA, PB, PC, PD) do {                                   \
        const float pivot = dpp_movf<((K) & 3) * 0x55>(PA[0]);               \
        nb += !(fabsf(pivot) >= tau);                                        \
        DAC *= (double)pivot;                                                \
        const float pinv = __builtin_amdgcn_rcpf(pivot);                     \
        const float fa = (l > ((K) & 3)) ? PA[0] * pinv : 0.0f;              \
        const float fb = PB[0] * pinv;                                       \
        const float fc = PC[0] * pinv;                                       \
        const float fd = PD[0] * pinv;                                       \
        _Pragma("unroll")                                                    \
        for (int j = 1; j <= 15 - (K); ++j) {                                \
            const float pv = dpp_movf<((K) & 3) * 0x55>(PA[j]);              \
            PA[j - 1] = fmaf(-fa, pv, PA[j]);                                \
            PB[j - 1] = fmaf(-fb, pv, PB[j]);                                \
            PC[j - 1] = fmaf(-fc, pv, PC[j]);                                \
            PD[j - 1] = fmaf(-fd, pv, PD[j]);                                \
        } } while (0)

#define STEP3(K, DAC, PA, PB, PC) do {                                       \
        const float pivot = dpp_movf<((K) & 3) * 0x55>(PA[0]);               \
        nb += !(fabsf(pivot) >= tau);                                        \
        DAC *= (double)pivot;                                                \
        const float pinv = __builtin_amdgcn_rcpf(pivot);                     \
        const float fa = (l > ((K) & 3)) ? PA[0] * pinv : 0.0f;              \
        const float fb = PB[0] * pinv;                                       \
        const float fc = PC[0] * pinv;                                       \
        _Pragma("unroll")                                                    \
        for (int j = 1; j <= 15 - (K); ++j) {                                \
            const float pv = dpp_movf<((K) & 3) * 0x55>(PA[j]);              \
            PA[j - 1] = fmaf(-fa, pv, PA[j]);                                \
            PB[j - 1] = fmaf(-fb, pv, PB[j]);                                \
            PC[j - 1] = fmaf(-fc, pv, PC[j]);                                \
        } } while (0)

#define STEP2(K, DAC, PA, PB) do {                                           \
        const float pivot = dpp_movf<((K) & 3) * 0x55>(PA[0]);               \
        nb += !(fabsf(pivot) >= tau);                                        \
        DAC *= (double)pivot;                                                \
        const float pinv = __builtin_amdgcn_rcpf(pivot);                     \
        const float fa = (l > ((K) & 3)) ? PA[0] * pinv : 0.0f;              \
        const float fb = PB[0] * pinv;                                       \
        _Pragma("unroll")                                                    \
        for (int j = 1; j <= 15 - (K); ++j) {                                \
            const float pv = dpp_movf<((K) & 3) * 0x55>(PA[j]);              \
            PA[j - 1] = fmaf(-fa, pv, PA[j]);                                \
            PB[j - 1] = fmaf(-fb, pv, PB[j]);                                \
        } } while (0)

#define STEP1(K, DAC, PA) do {                                               \
        const float pivot = dpp_movf<((K) & 3) * 0x55>(PA[0]);               \
        nb += !(fabsf(pivot) >= tau);                                        \
        DAC *= (double)pivot;                                                \
        const float pinv = __builtin_amdgcn_rcpf(pivot);                     \
        const float fa = (l > ((K) & 3)) ? PA[0] * pinv : 0.0f;              \
        _Pragma("unroll")                                                    \
        for (int j = 1; j <= 15 - (K); ++j) {                                \
            const float pv = dpp_movf<((K) & 3) * 0x55>(PA[j]);              \
            PA[j - 1] = fmaf(-fa, pv, PA[j]);                                \
        } } while (0)

    double deta = 1.0, detb = 1.0;
    bool domix = false;

    #pragma unroll 1
    for (int attempt = 0; attempt < 2; ++attempt) {
        if (attempt) {   // cold, PER-WAVE, barrier-free: rebuild + mix flagged
            unsigned long long m = mask;
            if (l & 1) { m &= m - 1; }
            if (l & 2) { m &= m - 1; m &= m - 1; }
            const int s0 = m ? (int)__builtin_ctzll(m) : 0;
            m &= m - 1; m &= m - 1; m &= m - 1; m &= m - 1;
            const int s1 = m ? (int)__builtin_ctzll(m) : 0;
            m &= m - 1; m &= m - 1; m &= m - 1; m &= m - 1;
            const int s2 = m ? (int)__builtin_ctzll(m) : 0;
            m &= m - 1; m &= m - 1; m &= m - 1; m &= m - 1;
            const int s3 = m ? (int)__builtin_ctzll(m) : 0;
            BUILD_ROW(R0, s0);
            BUILD_ROW(R1, s1);
            BUILD_ROW(R2, s2);
            BUILD_ROW(R3, s3);
            if (domix) {
                const bool z = (l == 0);
                #pragma unroll
                for (int j = 0; j < 16; ++j) {
                    const float w0 = z ? R1[j] : R0[j];
                    const float wv = z ? R2[j] : R1[j];
                    const float w2 = z ? R3[j] : R2[j];
                    const float w3 = z ? R0[j] : R3[j];
                    R0[j] = fmaf(0.5f, dpp_movf<0x39>(w0), R0[j]);
                    R1[j] = fmaf(0.5f, dpp_movf<0x39>(wv), R1[j]);
                    R2[j] = fmaf(0.5f, dpp_movf<0x39>(w2), R2[j]);
                    R3[j] = fmaf(0.5f, dpp_movf<0x39>(w3), R3[j]);
                }
            }
        }

        // ---- matrix scale for pivot-quality flag (quad-uniform) ----
        float mm = 0.0f;
        #pragma unroll
        for (int j = 0; j < 16; ++j) {
            mm = fmaxf(mm, fmaxf(fmaxf(fabsf(R0[j]), fabsf(R1[j])),
                                 fmaxf(fabsf(R2[j]), fabsf(R3[j]))));
        }
        mm = fmaxf(mm, dpp_movf<0xB1>(mm));   // quad_perm[1,0,3,2]
        mm = fmaxf(mm, dpp_movf<0x4E>(mm));   // quad_perm[2,3,0,1]
        const float tau = 1e-4f * mm;

        deta = 1.0; detb = 1.0;
        int nb = 0;

        STEP4(0,  deta, R0, R1, R2, R3);
        STEP4(1,  detb, R0, R1, R2, R3);
        STEP4(2,  deta, R0, R1, R2, R3);
        STEP4(3,  detb, R0, R1, R2, R3);
        STEP3(4,  deta, R1, R2, R3);
        STEP3(5,  detb, R1, R2, R3);
        STEP3(6,  deta, R1, R2, R3);
        STEP3(7,  detb, R1, R2, R3);
        STEP2(8,  deta, R2, R3);
        STEP2(9,  detb, R2, R3);
        STEP2(10, deta, R2, R3);
        STEP2(11, detb, R2, R3);
        STEP1(12, deta, R3);
        STEP1(13, detb, R3);
        STEP1(14, deta, R3);
        STEP1(15, detb, R3);

        if (attempt == 0) {
            if (!__any(nb != 0)) break;   // per-wave; retry path has no barriers
            domix = (nb != 0);            // only flagged quads get the mix
        }
    }
#undef STEP1
#undef STEP2
#undef STEP3
#undef STEP4
#undef BUILD_ROW
#undef COMPUTE_DET
#undef SLICE_WRITE
#undef SLICE_LOAD

    // ---- combine: det_d (uniform in quad) dotted with bf ----
    float detf = (float)(deta * detb);
    if (domix) detf *= (65536.0f / 65535.0f);   // / det(I + 0.5*C16)
    float acc = (l == 0) ? detf * bf[d] : 0.0f;
    acc += __shfl_xor(acc, 4);
    acc += __shfl_xor(acc, 8);
    acc += __shfl_xor(acc, 16);
    acc += __shfl_xor(acc, 32);
    if (lane == 0) out[b] = empty ? 0.0f : acc;
}

extern "C" void kernel_launch(void* const* d_in, const int* in_sizes, int n_in,
                              void* d_out, int out_size, void* d_ws, size_t ws_size,
                              hipStream_t stream) {
    const float* x  = (const float*)d_in[0];
    const float* W1 = (const float*)d_in[1];
    const float* b1 = (const float*)d_in[2];
    const float* W2 = (const float*)d_in[3];
    const float* b2 = (const float*)d_in[4];
    const float* Wg = (const float*)d_in[5];
    const float* bg = (const float*)d_in[6];
    const float* bf = (const float*)d_in[7];
    float* out = (float*)d_out;

    const int B = in_sizes[0] / 64;
    const int blocks = (B + 7) / 8;   // 8 samples (waves) per 512-thread block
    backflow_kernel<<<blocks, 512, 0, stream>>>(x, W1, b1, W2, b2, Wg, bg, bf, out, B);
}

// Round 18
// 45.741 us; speedup vs baseline: 1.6675x; 1.6675x over previous
//
#include <hip/hip_runtime.h>

// Backflow: out[b] = sum_d det(g[b,d]) * bf[d]
//   g[b,d][i][j] = sum_h h2[b,h]*Wg[h,d,sel[b,i],j] + bg[d,sel[b,i],j]
// B=8192, O=64, E=16, D=16, H=4.
//
// R18 = R13 (champion, 46.2us) with ONE change: stage loop unrolled by 2
// with NO sched_barrier, so the compiler overlaps det k+1's 5 loads with
// det k's contract+LDS-write (R13 serialized every det's ~400cy L2 trip).
// One wave per block/sample. Two lane roles:
//  LOAD role lane=r*4+c: loads Wg[h][d][sel_r][4c..] (fully-consumed 64B
//    lines), h2-weighted sum in regs, staged into 8KB LDS (8 dets/half,
//    chunk swizzle c^(d&3)).
//  LU role lane=4d+l: reads rows l,l+4,l+8,l+12 of det d from LDS; then
//    fully-unrolled triangular unpivoted LU (zero DS ops, static DPP
//    quad_perm broadcasts, column-shift, per-round array retirement).
// Retry (tau=1e-4*mat_max): rebuild via per-lane gather (cold), premul
// M = I + 0.5*C16 (det = 1-2^-16), re-run LU, rescale.
// Lessons: R6/R15 launch-bounds VGPR caps -> spill. R7 macro hygiene.
// R12 rule #20 (runtime-indexed R arrays -> scratch). R14-R17: occupancy,
// phase-locking, and coop staging all lose to R13's simple gather.

template <int CTRL>
__device__ __forceinline__ float dpp_movf(float v) {
    return __int_as_float(__builtin_amdgcn_update_dpp(
        0, __float_as_int(v), CTRL, 0xF, 0xF, true));
}

__global__ __launch_bounds__(64) void backflow_kernel(
    const float* __restrict__ x,    // (B,64)
    const float* __restrict__ W1,   // (64,4)
    const float* __restrict__ b1,   // (4,)
    const float* __restrict__ W2,   // (4,4)
    const float* __restrict__ b2,   // (4,)
    const float* __restrict__ Wg,   // (4,16,64,16)
    const float* __restrict__ bg,   // (16,64,16)
    const float* __restrict__ bf,   // (16,1)
    float* __restrict__ out,        // (B,)
    int B)
{
    const int lane = threadIdx.x;   // one wave per block
    const int b    = blockIdx.x;
    if (b >= B) return;
    const int d = lane >> 2;   // LU: det index; LOAD: row index r (same bits)
    const int l = lane & 3;    // LU: lane-in-quad; LOAD: chunk index c

    __shared__ float4 smem[512];   // 8 KB: 8 dets x 16 rows x 4 chunks

    // ---- occupied-orbital mask ----
    const float xv = x[b * 64 + lane];
    const unsigned long long mask = __ballot(xv != 0.0f);
    const bool empty = ((mask & ~1ull) == 0ull);

    // ---- h1 = relu(x @ W1 + b1): 64-lane butterfly ----
    const float4 w1 = reinterpret_cast<const float4*>(W1)[lane];
    float c0 = xv * w1.x, c1 = xv * w1.y, c2 = xv * w1.z, c3 = xv * w1.w;
    #pragma unroll
    for (int off = 32; off >= 1; off >>= 1) {
        c0 += __shfl_xor(c0, off);
        c1 += __shfl_xor(c1, off);
        c2 += __shfl_xor(c2, off);
        c3 += __shfl_xor(c3, off);
    }
    const float h10 = fmaxf(c0 + b1[0], 0.0f);
    const float h11 = fmaxf(c1 + b1[1], 0.0f);
    const float h12 = fmaxf(c2 + b1[2], 0.0f);
    const float h13 = fmaxf(c3 + b1[3], 0.0f);

    // ---- h2 = relu(h1 @ W2 + b2) ----
    float h2[4];
    #pragma unroll
    for (int j = 0; j < 4; ++j) {
        float v = b2[j];
        v = fmaf(h10, W2[0 * 4 + j], v);
        v = fmaf(h11, W2[1 * 4 + j], v);
        v = fmaf(h12, W2[2 * 4 + j], v);
        v = fmaf(h13, W2[3 * 4 + j], v);
        h2[j] = fmaxf(v, 0.0f);
    }

    // ---- LOAD-role selected row: sel_r for r = lane>>2 (skip r set bits) ----
    unsigned long long mr = mask;
    #pragma unroll
    for (int i = 0; i < 15; ++i) if (i < d) mr &= mr - 1;
    const int selr = mr ? (int)__builtin_ctzll(mr) : 0;
    const int rowoff = selr * 4 + l;   // float4 index: row selr, chunk c=l

    const float4* wgp = reinterpret_cast<const float4*>(Wg);
    const float4* bgp = reinterpret_cast<const float4*>(bg);

    float R0[16], R1[16], R2[16], R3[16];

    // ---- one det's coalesced build + LDS stage (arithmetic order = R13) ----
#define STAGE_ONE(DS) do {                                                   \
        const int _ds = (DS);                                                \
        const float4 wb  = bgp[_ds * 256 + rowoff];                          \
        const float4 w3  = wgp[(48 + _ds) * 256 + rowoff];                   \
        const float4 w2c = wgp[(32 + _ds) * 256 + rowoff];                   \
        const float4 wv1 = wgp[(16 + _ds) * 256 + rowoff];                   \
        const float4 w0  = wgp[_ds * 256 + rowoff];                          \
        float4 a;                                                            \
        a.x = fmaf(h2[0],w0.x, fmaf(h2[1],wv1.x, fmaf(h2[2],w2c.x, fmaf(h2[3],w3.x, wb.x)))); \
        a.y = fmaf(h2[0],w0.y, fmaf(h2[1],wv1.y, fmaf(h2[2],w2c.y, fmaf(h2[3],w3.y, wb.y)))); \
        a.z = fmaf(h2[0],w0.z, fmaf(h2[1],wv1.z, fmaf(h2[2],w2c.z, fmaf(h2[3],w3.z, wb.z)))); \
        a.w = fmaf(h2[0],w0.w, fmaf(h2[1],wv1.w, fmaf(h2[2],w2c.w, fmaf(h2[3],w3.w, wb.w)))); \
        smem[(_ds & 7) * 64 + d * 4 + (l ^ (_ds & 3))] = a;                  \
    } while (0)

    // ---- coalesced staged build: 2 halves of 8 dets through 8KB LDS ----
    {
        #pragma unroll 1
        for (int half = 0; half < 2; ++half) {
            // R18: 2 dets per iteration, NO sched_barrier -> the scheduler
            // issues both dets' 10 loads before the first consume (pipeline).
            #pragma unroll 1
            for (int dd = 0; dd < 4; ++dd) {
                STAGE_ONE(half * 8 + 2 * dd);
                STAGE_ONE(half * 8 + 2 * dd + 1);
            }
            __syncthreads();
            if ((d >> 3) == half) {
#define RD_ROWS(RW, S) do { _Pragma("unroll")                                 \
                for (int q = 0; q < 4; ++q) {                                 \
                    const float4 t = smem[(d & 7) * 64 + (l + 4 * (S)) * 4 + (q ^ (d & 3))]; \
                    RW[q*4+0] = t.x; RW[q*4+1] = t.y;                         \
                    RW[q*4+2] = t.z; RW[q*4+3] = t.w;                         \
                } } while (0)
                RD_ROWS(R0, 0);
                RD_ROWS(R1, 1);
                RD_ROWS(R2, 2);
                RD_ROWS(R3, 3);
#undef RD_ROWS
            }
            __syncthreads();
        }
    }

    // ---- retry-path rebuild (cold): per-lane gather; q-loop FULLY unrolled
    //      (static RW indices — rule #20) ----
#define BUILD_ROW(RW, SQ) do {                                                   \
    const float* base = Wg + ((size_t)d * 64 + (SQ)) * 16;                       \
    const float4* p0 = reinterpret_cast<const float4*>(base);                    \
    const float4* p1 = reinterpret_cast<const float4*>(base + 16384);            \
    const float4* p2 = reinterpret_cast<const float4*>(base + 32768);            \
    const float4* p3 = reinterpret_cast<const float4*>(base + 49152);            \
    const float4* pb = reinterpret_cast<const float4*>(bg + ((size_t)d * 64 + (SQ)) * 16); \
    _Pragma("unroll")                                                            \
    for (int q = 0; q < 4; ++q) {                                                \
        const float4 a0 = p0[q], a1 = p1[q], a2 = p2[q], a3 = p3[q], ab = pb[q]; \
        RW[q*4+0] = fmaf(h2[0],a0.x, fmaf(h2[1],a1.x, fmaf(h2[2],a2.x, fmaf(h2[3],a3.x, ab.x)))); \
        RW[q*4+1] = fmaf(h2[0],a0.y, fmaf(h2[1],a1.y, fmaf(h2[2],a2.y, fmaf(h2[3],a3.y, ab.y)))); \
        RW[q*4+2] = fmaf(h2[0],a0.z, fmaf(h2[1],a1.z, fmaf(h2[2],a2.z, fmaf(h2[3],a3.z, ab.z)))); \
        RW[q*4+3] = fmaf(h2[0],a0.w, fmaf(h2[1],a1.w, fmaf(h2[2],a2.w, fmaf(h2[3],a3.w, ab.w)))); \
    } } while (0)

    // ---- matrix scale for pivot-quality flag (quad-uniform) ----
    float mm = 0.0f;
    #pragma unroll
    for (int j = 0; j < 16; ++j) {
        mm = fmaxf(mm, fmaxf(fmaxf(fabsf(R0[j]), fabsf(R1[j])),
                             fmaxf(fabsf(R2[j]), fabsf(R3[j]))));
    }
    mm = fmaxf(mm, dpp_movf<0xB1>(mm));   // quad_perm[1,0,3,2]
    mm = fmaxf(mm, dpp_movf<0x4E>(mm));   // quad_perm[2,3,0,1]
    const float tau = 1e-4f * mm;

    // ---- triangular unpivoted LU steps (K static everywhere) ----
#define STEP4(K, DAC, PA, PB, PC, PD) do {                                   \
        const float pivot = dpp_movf<((K) & 3) * 0x55>(PA[0]);               \
        nb += !(fabsf(pivot) >= tau);                                        \
        DAC *= (double)pivot;                                                \
        const float pinv = __builtin_amdgcn_rcpf(pivot);                     \
        const float fa = (l > ((K) & 3)) ? PA[0] * pinv : 0.0f;              \
        const float fb = PB[0] * pinv;                                       \
        const float fc = PC[0] * pinv;                                       \
        const float fd = PD[0] * pinv;                                       \
        _Pragma("unroll")                                                    \
        for (int j = 1; j <= 15 - (K); ++j) {                                \
            const float pv = dpp_movf<((K) & 3) * 0x55>(PA[j]);              \
            PA[j - 1] = fmaf(-fa, pv, PA[j]);                                \
            PB[j - 1] = fmaf(-fb, pv, PB[j]);                                \
            PC[j - 1] = fmaf(-fc, pv, PC[j]);                                \
            PD[j - 1] = fmaf(-fd, pv, PD[j]);                                \
        } } while (0)

#define STEP3(K, DAC, PA, PB, PC) do {                                       \
        const float pivot = dpp_movf<((K) & 3) * 0x55>(PA[0]);               \
        nb += !(fabsf(pivot) >= tau);                                        \
        DAC *= (double)pivot;                                                \
        const float pinv = __builtin_amdgcn_rcpf(pivot);                     \
        const float fa = (l > ((K) & 3)) ? PA[0] * pinv : 0.0f;              \
        const float fb = PB[0] * pinv;                                       \
        const float fc = PC[0] * pinv;                                       \
        _Pragma("unroll")                                                    \
        for (int j = 1; j <= 15 - (K); ++j) {                                \
            const float pv = dpp_movf<((K) & 3) * 0x55>(PA[j]);              \
            PA[j - 1] = fmaf(-fa, pv, PA[j]);                                \
            PB[j - 1] = fmaf(-fb, pv, PB[j]);                                \
            PC[j - 1] = fmaf(-fc, pv, PC[j]);                                \
        } } while (0)

#define STEP2(K, DAC, PA, PB) do {                                           \
        const float pivot = dpp_movf<((K) & 3) * 0x55>(PA[0]);               \
        nb += !(fabsf(pivot) >= tau);                                        \
        DAC *= (double)pivot;                                                \
        const float pinv = __builtin_amdgcn_rcpf(pivot);                     \
        const float fa = (l > ((K) & 3)) ? PA[0] * pinv : 0.0f;              \
        const float fb = PB[0] * pinv;                                       \
        _Pragma("unroll")                                                    \
        for (int j = 1; j <= 15 - (K); ++j) {                                \
            const float pv = dpp_movf<((K) & 3) * 0x55>(PA[j]);              \
            PA[j - 1] = fmaf(-fa, pv, PA[j]);                                \
            PB[j - 1] = fmaf(-fb, pv, PB[j]);                                \
        } } while (0)

#define STEP1(K, DAC, PA) do {                                               \
        const float pivot = dpp_movf<((K) & 3) * 0x55>(PA[0]);               \
        nb += !(fabsf(pivot) >= tau);                                        \
        DAC *= (double)pivot;                                                \
        const float pinv = __builtin_amdgcn_rcpf(pivot);                     \
        const float fa = (l > ((K) & 3)) ? PA[0] * pinv : 0.0f;              \
        _Pragma("unroll")                                                    \
        for (int j = 1; j <= 15 - (K); ++j) {                                \
            const float pv = dpp_movf<((K) & 3) * 0x55>(PA[j]);              \
            PA[j - 1] = fmaf(-fa, pv, PA[j]);                                \
        } } while (0)

    double deta, detb;
    bool   retried = false;

    #pragma unroll 1
    for (int attempt = 0; attempt < 2; ++attempt) {
        if (attempt) {   // cold: rebuild via gather + premultiply M = I + 0.5*C16
            unsigned long long m = mask;
            if (l & 1) { m &= m - 1; }
            if (l & 2) { m &= m - 1; m &= m - 1; }
            const int s0 = m ? (int)__builtin_ctzll(m) : 0;
            m &= m - 1; m &= m - 1; m &= m - 1; m &= m - 1;
            const int s1 = m ? (int)__builtin_ctzll(m) : 0;
            m &= m - 1; m &= m - 1; m &= m - 1; m &= m - 1;
            const int s2 = m ? (int)__builtin_ctzll(m) : 0;
            m &= m - 1; m &= m - 1; m &= m - 1; m &= m - 1;
            const int s3 = m ? (int)__builtin_ctzll(m) : 0;
            BUILD_ROW(R0, s0);
            BUILD_ROW(R1, s1);
            BUILD_ROW(R2, s2);
            BUILD_ROW(R3, s3);
            const bool z = (l == 0);
            #pragma unroll
            for (int j = 0; j < 16; ++j) {
                const float w0 = z ? R1[j] : R0[j];
                const float wv = z ? R2[j] : R1[j];
                const float w2 = z ? R3[j] : R2[j];
                const float w3 = z ? R0[j] : R3[j];
                R0[j] = fmaf(0.5f, dpp_movf<0x39>(w0), R0[j]);
                R1[j] = fmaf(0.5f, dpp_movf<0x39>(wv), R1[j]);
                R2[j] = fmaf(0.5f, dpp_movf<0x39>(w2), R2[j]);
                R3[j] = fmaf(0.5f, dpp_movf<0x39>(w3), R3[j]);
            }
            retried = true;
        }
        deta = 1.0; detb = 1.0;
        int nb = 0;

        STEP4(0,  deta, R0, R1, R2, R3);
        STEP4(1,  detb, R0, R1, R2, R3);
        STEP4(2,  deta, R0, R1, R2, R3);
        STEP4(3,  detb, R0, R1, R2, R3);
        STEP3(4,  deta, R1, R2, R3);
        STEP3(5,  detb, R1, R2, R3);
        STEP3(6,  deta, R1, R2, R3);
        STEP3(7,  detb, R1, R2, R3);
        STEP2(8,  deta, R2, R3);
        STEP2(9,  detb, R2, R3);
        STEP2(10, deta, R2, R3);
        STEP2(11, detb, R2, R3);
        STEP1(12, deta, R3);
        STEP1(13, detb, R3);
        STEP1(14, deta, R3);
        STEP1(15, detb, R3);

        if (nb == 0) break;   // nb is quad-uniform; bad quads loop again
    }
#undef STEP1
#undef STEP2
#undef STEP3
#undef STEP4
#undef BUILD_ROW
#undef STAGE_ONE

    // ---- combine: det_d (uniform in quad) dotted with bf ----
    float detf = (float)(deta * detb);
    if (retried) detf *= (65536.0f / 65535.0f);   // / det(I + 0.5*C16)
    float acc = (l == 0) ? detf * bf[d] : 0.0f;
    acc += __shfl_xor(acc, 4);
    acc += __shfl_xor(acc, 8);
    acc += __shfl_xor(acc, 16);
    acc += __shfl_xor(acc, 32);
    if (lane == 0) out[b] = empty ? 0.0f : acc;
}

extern "C" void kernel_launch(void* const* d_in, const int* in_sizes, int n_in,
                              void* d_out, int out_size, void* d_ws, size_t ws_size,
                              hipStream_t stream) {
    const float* x  = (const float*)d_in[0];
    const float* W1 = (const float*)d_in[1];
    const float* b1 = (const float*)d_in[2];
    const float* W2 = (const float*)d_in[3];
    const float* b2 = (const float*)d_in[4];
    const float* Wg = (const float*)d_in[5];
    const float* bg = (const float*)d_in[6];
    const float* bf = (const float*)d_in[7];
    float* out = (float*)d_out;

    const int B = in_sizes[0] / 64;
    backflow_kernel<<<B, 64, 0, stream>>>(x, W1, b1, W2, b2, Wg, bg, bf, out, B);
}